// Round 10
// baseline (191.317 us; speedup 1.0000x reference)
//
#include <hip/hip_runtime.h>

// RecursiveNN: 11-level binary tree, shared linear map W(128x256)+b, bf16 MFMA.
// Evidence ledger (r0-r9): phase floor ~36us at pair-level ladder; quad-level
// algebra (W2 = [WlWl|WlWr|WrWl|WrWr], b2=(Wl+Wr)b+b) verified correct in r9
// (passed, absmax 0.0039->0.0024) but regressed 42->55us from two causes:
//   (a) 3.5M LDS bank conflicts: perm row s*NOUT+me = consecutive-row reads.
//       Fix: R = 2*me+(s&1)+32*(s>>1) reproduces the proven stride-2 pattern.
//   (b) streamed nl=1 W2 frags put a global load on the MFMA critical path.
//       Fix: both halves resident (128 VGPR), funded by DMA gather.
// Gather: global_load_lds (bf16 rows = pure copy): linear LDS dest, quad-perm
// R and T2 XOR swizzle (chunk ^= (row>>1)&7) folded into the per-lane GLOBAL
// source address (pre-swizzled-source). Unpadded 256B rows; 3x16KB LDS ->
// 3 blocks/CU. Counted-vmcnt schedule (verified T3/T4): issue G0,G1;
// vmcnt(4)+raw-bar; L12(c0) w/ G1 in flight; vmcnt(0); issue G2; ...
// prep + tree32 byte-identical to r9 (both proven).
// launch_bounds(256,3); reg estimate ~160 <= 170. Spill tripwire: WRITE_SIZE.

typedef __bf16 bf16x8 __attribute__((ext_vector_type(8)));
typedef __bf16 bf16x4 __attribute__((ext_vector_type(4)));
typedef float f32x4 __attribute__((ext_vector_type(4)));

#define STRIDE 136  // tree32 only: 128 cols + 8 pad bf16 (272B rows)

// Raw barrier: orders LDS ops without draining vmcnt (in-flight DMAs survive).
#define BARRIER() do {                                          \
    asm volatile("s_waitcnt lgkmcnt(0)" ::: "memory");          \
    __builtin_amdgcn_s_barrier();                               \
} while (0)

// Counted-vmcnt barrier: wait until <=N VMEM ops outstanding, then barrier.
#define VMBARRIER(N) do {                                                   \
    asm volatile("s_waitcnt vmcnt(" #N ") lgkmcnt(0)" ::: "memory");        \
    __builtin_amdgcn_s_barrier();                                           \
} while (0)

// 16B-per-lane global->LDS DMA: LDS dest = lp (wave-uniform) + lane*16.
__device__ __forceinline__ void dma16(const __bf16* g, __bf16* l) {
    __builtin_amdgcn_global_load_lds(
        (const __attribute__((address_space(1))) unsigned int*)g,
        (__attribute__((address_space(3))) unsigned int*)l, 16, 0, 0);
}

// prep: blocks 0-15 pack W1 -> wpack1; blocks 16-47 compute+pack W2
// (f2=nl*16+kk, quadrant s=d>>7: W2[o][d] = sum_k W[o,(s>>1)*128+k] *
// W[k,(s&1)*128+(d&127)]); block 48: b2 = (Wl+Wr)b + b. All blocks
// grid-stride convert emb fp32 -> bf16 etab.  [byte-identical to r9]
__global__ void prep_kernel(const float* __restrict__ W,
                            const float* __restrict__ bias,
                            const float* __restrict__ emb,
                            __bf16* __restrict__ wpack1,
                            __bf16* __restrict__ wpack2,
                            float* __restrict__ b2,
                            __bf16* __restrict__ etab, int n8) {
    const int tid = threadIdx.x;
    const int bx = blockIdx.x;
    const int wv = tid >> 6, l = tid & 63;
    if (bx < 16) {
        const int nl = bx >> 3, kk = bx & 7;
        const int o = ((wv << 1) + nl) * 16 + (l & 15);
        const int d = kk * 32 + ((l >> 4) << 3);
        const float* src = W + o * 256 + d;
        bf16x8 h;
#pragma unroll
        for (int j = 0; j < 8; ++j) h[j] = (__bf16)src[j];
        *(bf16x8*)(wpack1 + (size_t)(bx * 256 + tid) * 8) = h;
    } else if (bx < 48) {
        const int f2 = bx - 16;                  // 0..31
        const int nl = f2 >> 4, kk = f2 & 15;
        const int o = ((wv << 1) + nl) * 16 + (l & 15);
        const int d = kk * 32 + ((l >> 4) << 3); // 0..511, 8-elem block
        const int s = d >> 7, c = d & 127;       // quadrant, inner col
        const float* wrow = W + o * 256 + (s >> 1) * 128;
        const float* wcol = W + (s & 1) * 128 + c;
        float a8[8] = {0, 0, 0, 0, 0, 0, 0, 0};
        for (int k = 0; k < 128; ++k) {
            const float wl = wrow[k];
            const float* wr = wcol + k * 256;
#pragma unroll
            for (int j = 0; j < 8; ++j) a8[j] += wl * wr[j];
        }
        bf16x8 h;
#pragma unroll
        for (int j = 0; j < 8; ++j) h[j] = (__bf16)a8[j];
        *(bf16x8*)(wpack2 + (size_t)(f2 * 256 + tid) * 8) = h;
    } else if (bx == 48) {
        if (tid < 128) {
            float acc = bias[tid];
            const float* wr = W + tid * 256;
            for (int k = 0; k < 128; ++k)
                acc += (wr[k] + wr[128 + k]) * bias[k];
            b2[tid] = acc;
        }
    }
    const int stride = gridDim.x * blockDim.x;
    for (int i = bx * blockDim.x + tid; i < n8; i += stride) {
        const float* s = emb + (size_t)i * 8;
        const f32x4 a = *(const f32x4*)s;
        const f32x4 b = *(const f32x4*)(s + 4);
        const bf16x4 ha = __builtin_convertvector(a, bf16x4);
        const bf16x4 hb = __builtin_convertvector(b, bf16x4);
        bf16x8 h;
#pragma unroll
        for (int j = 0; j < 4; ++j) { h[j] = ha[j]; h[4 + j] = hb[j]; }
        *(bf16x8*)(etab + (size_t)i * 8) = h;
    }
}

// ---- tree128: swizzled unpadded LDS (256B rows) ----
// Logical (row, chunk c16) lives at phys elem row*128 + ((c16 ^ ((row>>1)&7))*8).
// Quad read of child s, node me: row = 2*me + (s&1) + 32*(s>>1) -> stride-2
// rows per 16-lane group; XOR term = me&7 -> 8 distinct 16B slots = 2-way free.
template <int NOUT>
__device__ __forceinline__ void quad_acc_swz(
    const __bf16* src, const bf16x8* w2r, const float* b2v,
    int q, int lm, f32x4 (&a2)[2])
{
    const int me = (NOUT >= 16) ? lm : (lm < NOUT ? lm : 0);
    a2[0] = f32x4{ b2v[0], b2v[0], b2v[0], b2v[0] };
    a2[1] = f32x4{ b2v[1], b2v[1], b2v[1], b2v[1] };
#pragma unroll
    for (int kk = 0; kk < 16; ++kk) {
        const int s = kk >> 2;
        const int row = 2 * me + (s & 1) + 32 * (s >> 1);
        const int cph = ((kk & 3) * 4 + q) ^ (me & 7);
        const bf16x8 af = *(const bf16x8*)&src[row * 128 + cph * 8];
        a2[0] = __builtin_amdgcn_mfma_f32_16x16x32_bf16(
            af, w2r[kk], a2[0], 0, 0, 0);
        a2[1] = __builtin_amdgcn_mfma_f32_16x16x32_bf16(
            af, w2r[16 + kk], a2[1], 0, 0, 0);
    }
}

// Kernel 1: one block = 256 leaves (2048 blocks). Quad ladder, 6 compute
// phases: 4x L12 (64 leaves -> 16 nodes into D), L34 (D -> E in bufA rows
// {0..7,32..39}), L56 (E -> 4 roots -> y).
// Gather: leaf l of a 64-chunk sits at row R(l) = 2*(l>>2)+(l&1)+32*((l>>1)&1);
// wave w DMAs LDS rows [16w,16w+16) linearly; lane picks global (leaf,chunk)
// via R^-1 + XOR so phys layout matches the read convention above.
template <bool BF>
__global__ __launch_bounds__(256, 3) void tree128_kernel(
    const int* __restrict__ wid, const float* __restrict__ emb,
    const __bf16* __restrict__ etab, const __bf16* __restrict__ wpack2,
    const float* __restrict__ b2, __bf16* __restrict__ yout)
{
    __shared__ __align__(16) __bf16 bufA[64 * 128];  // 16 KB
    __shared__ __align__(16) __bf16 bufB[64 * 128];  // 16 KB
    __shared__ __align__(16) __bf16 bufD[64 * 128];  // 16 KB -> 48 KB total
    const int tid = threadIdx.x;
    const int batch = blockIdx.x >> 3;   // 8 blocks (256 leaves) per batch
    const int pair = blockIdx.x & 7;
    const int wv = tid >> 6, ln = tid & 63, q = ln >> 4, lm = ln & 15;

    // Both W2 halves resident: 32 x 16B = 128 regs. No loads in compute phases.
    const bf16x8* wp2 = (const bf16x8*)wpack2;
    bf16x8 w2r[32];
#pragma unroll
    for (int f = 0; f < 32; ++f) w2r[f] = wp2[f * 256 + tid];
    float b2v[2];
    b2v[0] = b2[(2 * wv + 0) * 16 + lm];
    b2v[1] = b2[(2 * wv + 1) * 16 + lm];

    const int* wb = wid + batch * 2048 + pair * 256;

    // L12: quad level on gathered chunk c -> D.
    // D row for (c,q,r): node me2 = 4c+q, child s2 = r ->
    //   row = 8c+2q+(r&1)+32(r>>1); XOR term X = (4c+q)&7 (r-independent).
    auto L12 = [&](const __bf16* src, int c) {
        f32x4 a2[2];
        quad_acc_swz<16>(src, w2r, b2v, q, lm, a2);
        const int X = (4 * c + q) & 7;
#pragma unroll
        for (int nl = 0; nl < 2; ++nl) {
            const int col = (2 * wv + nl) * 16 + lm;
            const bf16x4 hv = __builtin_convertvector(a2[nl], bf16x4);
#pragma unroll
            for (int r = 0; r < 4; ++r) {
                const int row = 8 * c + 2 * q + (r & 1) + 32 * (r >> 1);
                bufD[row * 128 + (col ^ (X << 3))] = hv[r];
            }
        }
    };

    if constexpr (BF) {
        // Per-lane DMA params. Wave w covers LDS rows 16w+4k+(ln>>4), k=0..3.
        // leaf = R^-1(row) = ((row&31)>>1)*4 + (row>>5)*2 + (row&1).
        int ids[4][4];     // [gather][k]
        int rowk[4];
#pragma unroll
        for (int k = 0; k < 4; ++k) {
            const int row = 16 * wv + 4 * k + (ln >> 4);
            rowk[k] = row;
            const int leaf = ((row & 31) >> 1) * 4 + (row >> 5) * 2 + (row & 1);
#pragma unroll
            for (int g = 0; g < 4; ++g) ids[g][k] = wb[g * 64 + leaf];
        }
        __builtin_amdgcn_sched_barrier(0);  // pin preloads before DMA issues

        // One 64-row gather = 4 DMA instrs/wave (1KB each, linear LDS dest).
        // Source chunk pre-swizzled: c16 = (ln&15) ^ ((row>>1)&7).
        auto ISSUE = [&](const int (&idk)[4], __bf16* buf) {
#pragma unroll
            for (int k = 0; k < 4; ++k) {
                const int c16 = (ln & 15) ^ ((rowk[k] >> 1) & 7);
                const __bf16* gp = etab + (size_t)idk[k] * 128 + c16 * 8;
                __bf16* lp = buf + (16 * wv + 4 * k) * 128;  // wave-uniform
                dma16(gp, lp);
            }
        };

        ISSUE(ids[0], bufA);
        ISSUE(ids[1], bufB);
        VMBARRIER(4);           // G0 landed; G1 (4 DMAs) stays in flight
        L12(bufA, 0);
        VMBARRIER(0);           // G1 landed
        ISSUE(ids[2], bufA);    // A dead; G2 flies under L12(c1)
        L12(bufB, 1);
        VMBARRIER(0);           // G2 landed
        ISSUE(ids[3], bufB);    // B dead; G3 flies under L12(c2)
        L12(bufA, 2);
        VMBARRIER(0);           // G3 landed
        L12(bufB, 3);
        BARRIER();
    } else {
        // Fallback (ws too small): fp32 reg-staged gather, same swizzled LDS.
        f32x4 st[8];
        auto GISS = [&](int g) {
#pragma unroll
            for (int i = 0; i < 8; ++i) {
                const int row = (tid >> 5) + 8 * i;
                const int leaf =
                    ((row & 31) >> 1) * 4 + (row >> 5) * 2 + (row & 1);
                const int id = wb[g * 64 + leaf];
                st[i] = *(const f32x4*)(emb + (size_t)id * 128 + (tid & 31) * 4);
            }
        };
        auto GWR = [&](__bf16* dst) {
#pragma unroll
            for (int i = 0; i < 8; ++i) {
                const int row = (tid >> 5) + 8 * i;
                const int X = (row >> 1) & 7;
                *(bf16x4*)&dst[row * 128 + (((tid & 31) * 4) ^ (X << 3))] =
                    __builtin_convertvector(st[i], bf16x4);
            }
        };
        GISS(0); GWR(bufA); BARRIER();
        GISS(1); L12(bufA, 0); GWR(bufB); BARRIER();
        GISS(2); L12(bufB, 1); GWR(bufA); BARRIER();
        GISS(3); L12(bufA, 2); GWR(bufB); BARRIER();
        L12(bufB, 3); BARRIER();
    }

    // L34: D (64 rows) -> E (bufA rows 2q+(r&1)+32(r>>1) in {0..7,32..39}).
    {
        f32x4 a2[2];
        quad_acc_swz<16>(bufD, w2r, b2v, q, lm, a2);
#pragma unroll
        for (int nl = 0; nl < 2; ++nl) {
            const int col = (2 * wv + nl) * 16 + lm;
            const bf16x4 hv = __builtin_convertvector(a2[nl], bf16x4);
#pragma unroll
            for (int r = 0; r < 4; ++r) {
                const int row = 2 * q + (r & 1) + 32 * (r >> 1);
                bufA[row * 128 + (col ^ (q << 3))] = hv[r];  // X=(row>>1)&7=q
            }
        }
    }
    BARRIER();
    // L56: E (16 nodes) -> 4 roots straight to y (rows 0..3 at q==0).
    {
        f32x4 a2[2];
        quad_acc_swz<4>(bufA, w2r, b2v, q, lm, a2);
        __bf16* yrow = yout + (size_t)(batch * 32 + pair * 4) * 128;
#pragma unroll
        for (int nl = 0; nl < 2; ++nl) {
            const int col = (2 * wv + nl) * 16 + lm;
            if (q == 0) {
#pragma unroll
                for (int r = 0; r < 4; ++r)
                    yrow[r * 128 + col] = (__bf16)a2[nl][r];
            }
        }
    }
}

// ---- tree32: byte-identical to r9 (proven) ----
template <int NOUT>
__device__ __forceinline__ void quad_acc_res(
    const __bf16* src, const bf16x8* w2r,
    const float* b2v, int q, int lm, f32x4 (&acc)[2])
{
    const int me = (NOUT >= 16) ? lm : (lm < NOUT ? lm : 0);
    acc[0] = f32x4{ b2v[0], b2v[0], b2v[0], b2v[0] };
    acc[1] = f32x4{ b2v[1], b2v[1], b2v[1], b2v[1] };
#pragma unroll
    for (int kk = 0; kk < 16; ++kk) {
        const bf16x8 af = *(const bf16x8*)
            &src[((kk >> 2) * NOUT + me) * STRIDE + (kk & 3) * 32 + q * 8];
        acc[0] = __builtin_amdgcn_mfma_f32_16x16x32_bf16(
            af, w2r[kk], acc[0], 0, 0, 0);
        acc[1] = __builtin_amdgcn_mfma_f32_16x16x32_bf16(
            af, w2r[16 + kk], acc[1], 0, 0, 0);
    }
}

__global__ __launch_bounds__(256) void tree32_kernel(
    const __bf16* __restrict__ yin, const __bf16* __restrict__ wpack1,
    const __bf16* __restrict__ wpack2, const float* __restrict__ b2,
    const float* __restrict__ bias, float* __restrict__ out)
{
    __shared__ __align__(16) __bf16 buf0[32 * STRIDE];  // 8704 B
    __shared__ __align__(16) __bf16 buf1[8 * STRIDE];   // 2176 B
    const int tid = threadIdx.x;
    const int batch = blockIdx.x;
    const int wv = tid >> 6, ln = tid & 63, q = ln >> 4, lm = ln & 15;

    bf16x8 w2r[32];
    const bf16x8* wp2 = (const bf16x8*)wpack2;
#pragma unroll
    for (int f = 0; f < 32; ++f) w2r[f] = wp2[f * 256 + tid];
    bf16x8 w1r[16];
    const bf16x8* wp1 = (const bf16x8*)wpack1;
#pragma unroll
    for (int f = 0; f < 16; ++f) w1r[f] = wp1[f * 256 + tid];
    float b2v[2], b1v[2];
    b2v[0] = b2[(2 * wv + 0) * 16 + lm];
    b2v[1] = b2[(2 * wv + 1) * 16 + lm];
    b1v[0] = bias[(2 * wv + 0) * 16 + lm];
    b1v[1] = bias[(2 * wv + 1) * 16 + lm];

#pragma unroll
    for (int i = 0; i < 2; ++i) {
        const int flat = tid + 256 * i;
        const int o = flat >> 4;
        const int c8 = flat & 15;
        const bf16x8 v =
            *(const bf16x8*)(yin + (size_t)(batch * 32 + o) * 128 + c8 * 8);
        *(bf16x8*)&buf0[((o & 3) * 8 + (o >> 2)) * STRIDE + c8 * 8] = v;
    }
    __syncthreads();

    // Q1: 32 -> 8 (perm rows r*2+q for the NOUT=2 read).
    {
        f32x4 a2[2];
        quad_acc_res<8>(buf0, w2r, b2v, q, lm, a2);
#pragma unroll
        for (int nl = 0; nl < 2; ++nl) {
            const int col = (2 * wv + nl) * 16 + lm;
            const bf16x4 hv = __builtin_convertvector(a2[nl], bf16x4);
            if (q < 2) {
#pragma unroll
                for (int r = 0; r < 4; ++r)
                    buf1[(r * 2 + q) * STRIDE + col] = hv[r];
            }
        }
    }
    __syncthreads();
    // Q2: 8 -> 2 (plain rows 0,1 for the W1 final).
    {
        f32x4 a2[2];
        quad_acc_res<2>(buf1, w2r, b2v, q, lm, a2);
#pragma unroll
        for (int nl = 0; nl < 2; ++nl) {
            const int col = (2 * wv + nl) * 16 + lm;
            const bf16x4 hv = __builtin_convertvector(a2[nl], bf16x4);
            if (q == 0) {
#pragma unroll
                for (int r = 0; r < 2; ++r)
                    buf0[r * STRIDE + col] = hv[r];
            }
        }
    }
    __syncthreads();
    // Final: rows 0,1 (K=256, W1, bias b) -> fp32 root row.
    {
        f32x4 acc[2];
        acc[0] = f32x4{ b1v[0], b1v[0], b1v[0], b1v[0] };
        acc[1] = f32x4{ b1v[1], b1v[1], b1v[1], b1v[1] };
#pragma unroll
        for (int kh = 0; kh < 2; ++kh) {
            bf16x8 af[4];
#pragma unroll
            for (int j = 0; j < 4; ++j)
                af[j] = *(const bf16x8*)&buf0[kh * STRIDE + j * 32 + q * 8];
#pragma unroll
            for (int nl = 0; nl < 2; ++nl)
#pragma unroll
                for (int j = 0; j < 4; ++j)
                    acc[nl] = __builtin_amdgcn_mfma_f32_16x16x32_bf16(
                        af[j], w1r[nl * 8 + kh * 4 + j], acc[nl], 0, 0, 0);
        }
#pragma unroll
        for (int nl = 0; nl < 2; ++nl) {
            const int col = (2 * wv + nl) * 16 + lm;
            if (q == 0) out[(size_t)batch * 128 + col] = acc[nl][0];
        }
    }
}

extern "C" void kernel_launch(void* const* d_in, const int* in_sizes, int n_in,
                              void* d_out, int out_size, void* d_ws, size_t ws_size,
                              hipStream_t stream) {
    const int*   wid = (const int*)d_in[0];      // (256, 2048) int32
    const float* emb = (const float*)d_in[1];    // (100000, 128) fp32
    const float* W   = (const float*)d_in[2];    // (128, 256) fp32
    const float* b   = (const float*)d_in[3];    // (128,) fp32
    float* out = (float*)d_out;                  // (256, 128) fp32

    __bf16* wpack1 = (__bf16*)d_ws;              // 32768 bf16 = 64 KB
    __bf16* wpack2 = wpack1 + 32768;             // 65536 bf16 = 128 KB
    float*  b2     = (float*)(wpack2 + 65536);   // 128 f32 = 512 B
    __bf16* y      = (__bf16*)(b2 + 128);        // (256,32,128) bf16 = 2 MB
    __bf16* etab   = y + 256 * 32 * 128;         // (100000,128) bf16 = 25.6 MB

    const size_t need_full = (size_t)(32768 + 65536) * 2 + 512
                           + (size_t)256 * 32 * 128 * 2
                           + (size_t)100000 * 128 * 2;   // ~27.9 MB
    const bool bf = (ws_size >= need_full);
    const int n8 = bf ? (100000 * 128 / 8) : 0;

    prep_kernel<<<2048, 256, 0, stream>>>(W, b, emb, wpack1, wpack2, b2,
                                          etab, n8);
    if (bf)
        tree128_kernel<true><<<2048, 256, 0, stream>>>(
            wid, emb, etab, wpack2, b2, y);
    else
        tree128_kernel<false><<<2048, 256, 0, stream>>>(
            wid, emb, etab, wpack2, b2, y);
    tree32_kernel<<<256, 256, 0, stream>>>(y, wpack1, wpack2, b2, b, out);
}

// Round 11
// 140.001 us; speedup vs baseline: 1.3665x; 1.3665x over previous
//
#include <hip/hip_runtime.h>

// RecursiveNN: 11-level binary tree, shared linear map W(128x256)+b, bf16 MFMA.
// Evidence ledger (r0-r10):
//   - Quad algebra (W2=[WlWl|WlWr|WrWl|WrWr], b2=(Wl+Wr)b+b) VERIFIED (r9/r10
//     passed, absmax 0.0039->0.0024).
//   - STRIDE=136 padded LDS + stride-2-row reads: 0 conflicts over 9 rounds.
//     Both unpadded-XOR attempts (r9 perm, r10 swizzle) left 3.5-3.8M
//     conflicts: RULE: only measured-0-conflict address patterns allowed.
//   - r10 spill: w2r[32] (128 regs) + ids at (256,3) budget 170 -> 157MB
//     scratch. Fix: (256,2) budget 256; demand ~185 fits with slack.
//   - Occupancy weak lever (r4: 3->4 neutral) -> 2 blocks/CU acceptable.
//   - r8: reg-staged 16B/lane bf16 gather proven; pipelining depth neutral.
// This round: quad ladder (6 compute phases vs r6's 13) on the PROVEN padded
// layout; leaf/node perm row = 2*me+(s&1)+32*(s>>1) makes quad reads
// bit-identical to r6's step32 addresses. W2 resident as two 16-frag arrays
// (r0-r8 wf[16] AGPR pattern x2). prep + tree32 byte-identical to r9.

typedef __bf16 bf16x8 __attribute__((ext_vector_type(8)));
typedef __bf16 bf16x4 __attribute__((ext_vector_type(4)));
typedef float f32x4 __attribute__((ext_vector_type(4)));

#define STRIDE 136  // 128 cols + 8 pad bf16 = 272B rows; 0 LDS conflicts measured

// Raw barrier: orders LDS ops without draining vmcnt.
#define BARRIER() do {                                          \
    asm volatile("s_waitcnt lgkmcnt(0)" ::: "memory");          \
    __builtin_amdgcn_s_barrier();                               \
} while (0)

// prep: blocks 0-15 pack W1 -> wpack1; blocks 16-47 compute+pack W2
// (f2=nl*16+kk, quadrant s=d>>7: W2[o][d] = sum_k W[o,(s>>1)*128+k] *
// W[k,(s&1)*128+(d&127)]); block 48: b2 = (Wl+Wr)b + b. All blocks
// grid-stride convert emb fp32 -> bf16 etab.  [byte-identical to r9]
__global__ void prep_kernel(const float* __restrict__ W,
                            const float* __restrict__ bias,
                            const float* __restrict__ emb,
                            __bf16* __restrict__ wpack1,
                            __bf16* __restrict__ wpack2,
                            float* __restrict__ b2,
                            __bf16* __restrict__ etab, int n8) {
    const int tid = threadIdx.x;
    const int bx = blockIdx.x;
    const int wv = tid >> 6, l = tid & 63;
    if (bx < 16) {
        const int nl = bx >> 3, kk = bx & 7;
        const int o = ((wv << 1) + nl) * 16 + (l & 15);
        const int d = kk * 32 + ((l >> 4) << 3);
        const float* src = W + o * 256 + d;
        bf16x8 h;
#pragma unroll
        for (int j = 0; j < 8; ++j) h[j] = (__bf16)src[j];
        *(bf16x8*)(wpack1 + (size_t)(bx * 256 + tid) * 8) = h;
    } else if (bx < 48) {
        const int f2 = bx - 16;                  // 0..31
        const int nl = f2 >> 4, kk = f2 & 15;
        const int o = ((wv << 1) + nl) * 16 + (l & 15);
        const int d = kk * 32 + ((l >> 4) << 3); // 0..511, 8-elem block
        const int s = d >> 7, c = d & 127;       // quadrant, inner col
        const float* wrow = W + o * 256 + (s >> 1) * 128;
        const float* wcol = W + (s & 1) * 128 + c;
        float a8[8] = {0, 0, 0, 0, 0, 0, 0, 0};
        for (int k = 0; k < 128; ++k) {
            const float wl = wrow[k];
            const float* wr = wcol + k * 256;
#pragma unroll
            for (int j = 0; j < 8; ++j) a8[j] += wl * wr[j];
        }
        bf16x8 h;
#pragma unroll
        for (int j = 0; j < 8; ++j) h[j] = (__bf16)a8[j];
        *(bf16x8*)(wpack2 + (size_t)(f2 * 256 + tid) * 8) = h;
    } else if (bx == 48) {
        if (tid < 128) {
            float acc = bias[tid];
            const float* wr = W + tid * 256;
            for (int k = 0; k < 128; ++k)
                acc += (wr[k] + wr[128 + k]) * bias[k];
            b2[tid] = acc;
        }
    }
    const int stride = gridDim.x * blockDim.x;
    for (int i = bx * blockDim.x + tid; i < n8; i += stride) {
        const float* s = emb + (size_t)i * 8;
        const f32x4 a = *(const f32x4*)s;
        const f32x4 b = *(const f32x4*)(s + 4);
        const bf16x4 ha = __builtin_convertvector(a, bf16x4);
        const bf16x4 hb = __builtin_convertvector(b, bf16x4);
        bf16x8 h;
#pragma unroll
        for (int j = 0; j < 4; ++j) { h[j] = ha[j]; h[4 + j] = hb[j]; }
        *(bf16x8*)(etab + (size_t)i * 8) = h;
    }
}

// Quad-level accumulate on PADDED layout. Child s of node me lives at row
// 2*me + (s&1) + 32*(s>>1): reads are bit-identical to r6's step32
// (rows 2lm+kh in [0,32) and +32) - measured 0 conflicts. K-frag kk=4s+j
// reads cols (kk&3)*32 + q*8 (same col pattern as r0-r8).
template <int NOUT>
__device__ __forceinline__ void quad_acc(
    const __bf16* src, const bf16x8 (&wa)[16], const bf16x8 (&wb)[16],
    const float* b2v, int q, int lm, f32x4 (&a2)[2])
{
    const int me = (NOUT >= 16) ? lm : (lm < NOUT ? lm : 0);
    a2[0] = f32x4{ b2v[0], b2v[0], b2v[0], b2v[0] };
    a2[1] = f32x4{ b2v[1], b2v[1], b2v[1], b2v[1] };
#pragma unroll
    for (int kk = 0; kk < 16; ++kk) {
        const int s = kk >> 2;
        const int row = 2 * me + (s & 1) + 32 * (s >> 1);
        const bf16x8 af = *(const bf16x8*)
            &src[row * STRIDE + (kk & 3) * 32 + q * 8];
        a2[0] = __builtin_amdgcn_mfma_f32_16x16x32_bf16(
            af, wa[kk], a2[0], 0, 0, 0);
        a2[1] = __builtin_amdgcn_mfma_f32_16x16x32_bf16(
            af, wb[kk], a2[1], 0, 0, 0);
    }
}

// Kernel 1: one block = 256 leaves (2048 blocks). Quad ladder, 6 compute
// phases: 4x L12 (64 leaves -> 16 nodes into D), L34 (D -> E rows
// {0..7,32..39} of bufA), L56 (E -> 4 roots -> y).
// Gather: leaf l of a 64-chunk lands at row 2*(l>>2)+(l&1)+32*((l>>1)&1);
// reg-staged bf16 rows, 16 lanes x 16B each (r8-proven pattern).
template <bool BF>
__global__ __launch_bounds__(256, 2) void tree128_kernel(
    const int* __restrict__ wid, const float* __restrict__ emb,
    const __bf16* __restrict__ etab, const __bf16* __restrict__ wpack2,
    const float* __restrict__ b2, __bf16* __restrict__ yout)
{
    __shared__ __align__(16) __bf16 bufA[64 * STRIDE];  // 17408 B
    __shared__ __align__(16) __bf16 bufB[64 * STRIDE];  // 17408 B
    __shared__ __align__(16) __bf16 bufD[64 * STRIDE];  // 17408 B -> 52224 total
    const int tid = threadIdx.x;
    const int batch = blockIdx.x >> 3;   // 8 blocks (256 leaves) per batch
    const int pair = blockIdx.x & 7;
    const int wv = tid >> 6, ln = tid & 63, q = ln >> 4, lm = ln & 15;

    // Both W2 halves resident as two 16-frag arrays (proven wf[16] pattern x2).
    const bf16x8* wp2 = (const bf16x8*)wpack2;
    bf16x8 w2a[16], w2b[16];
#pragma unroll
    for (int f = 0; f < 16; ++f) w2a[f] = wp2[f * 256 + tid];
#pragma unroll
    for (int f = 0; f < 16; ++f) w2b[f] = wp2[(16 + f) * 256 + tid];
    float b2v[2];
    b2v[0] = b2[(2 * wv + 0) * 16 + lm];
    b2v[1] = b2[(2 * wv + 1) * 16 + lm];

    const int* wb = wid + batch * 2048 + pair * 256;

    // L12: quad level on gathered chunk c -> D.
    // Output node n = q*4+r (D-frag row map); global L3-node = 16c+n ->
    // next-level parent m = 4c+q, child s2 = r ->
    // D row = 2*(4c+q) + (r&1) + 32*(r>>1) = 8c+2q+(r&1)+32*(r>>1).
    auto L12 = [&](const __bf16* src, int c) {
        f32x4 a2[2];
        quad_acc<16>(src, w2a, w2b, b2v, q, lm, a2);
#pragma unroll
        for (int nl = 0; nl < 2; ++nl) {
            const int col = (2 * wv + nl) * 16 + lm;
            const bf16x4 hv = __builtin_convertvector(a2[nl], bf16x4);
#pragma unroll
            for (int r = 0; r < 4; ++r) {
                const int row = 8 * c + 2 * q + (r & 1) + 32 * (r >> 1);
                bufD[row * STRIDE + col] = hv[r];
            }
        }
    };

    if constexpr (BF) {
        // Row -> leaf inversion: m=(row&31)>>1, s=(row&1)+2*(row>>5),
        // leaf = 4m+s. Thread covers rows (tid>>4)+16i, 16 lanes x 16B/row.
        int ids[4][4];
#pragma unroll
        for (int i = 0; i < 4; ++i) {
            const int row = (tid >> 4) + 16 * i;
            const int leaf =
                4 * ((row & 31) >> 1) + (row & 1) + 2 * (row >> 5);
#pragma unroll
            for (int g = 0; g < 4; ++g) ids[g][i] = wb[g * 64 + leaf];
        }
        bf16x8 st[4];
        auto GISS = [&](int g) {
#pragma unroll
            for (int i = 0; i < 4; ++i)
                st[i] = *(const bf16x8*)
                    (etab + (size_t)ids[g][i] * 128 + (tid & 15) * 8);
        };
        auto GWR = [&](__bf16* dst) {
#pragma unroll
            for (int i = 0; i < 4; ++i) {
                const int row = (tid >> 4) + 16 * i;
                *(bf16x8*)&dst[row * STRIDE + (tid & 15) * 8] = st[i];
            }
        };
        GISS(0); GWR(bufA); BARRIER();
        GISS(1); L12(bufA, 0); GWR(bufB); BARRIER();
        GISS(2); L12(bufB, 1); GWR(bufA); BARRIER();
        GISS(3); L12(bufA, 2); GWR(bufB); BARRIER();
        L12(bufB, 3); BARRIER();
    } else {
        // Fallback: fp32 reg-staged gather (32 lanes x 16B per 512B row).
        f32x4 st[8];
        auto GISS = [&](int g) {
#pragma unroll
            for (int i = 0; i < 8; ++i) {
                const int row = (tid >> 5) + 8 * i;
                const int leaf =
                    4 * ((row & 31) >> 1) + (row & 1) + 2 * (row >> 5);
                const int id = wb[g * 64 + leaf];
                st[i] = *(const f32x4*)(emb + (size_t)id * 128 + (tid & 31) * 4);
            }
        };
        auto GWR = [&](__bf16* dst) {
#pragma unroll
            for (int i = 0; i < 8; ++i) {
                const int row = (tid >> 5) + 8 * i;
                *(bf16x4*)&dst[row * STRIDE + (tid & 31) * 4] =
                    __builtin_convertvector(st[i], bf16x4);
            }
        };
        GISS(0); GWR(bufA); BARRIER();
        GISS(1); L12(bufA, 0); GWR(bufB); BARRIER();
        GISS(2); L12(bufB, 1); GWR(bufA); BARRIER();
        GISS(3); L12(bufA, 2); GWR(bufB); BARRIER();
        L12(bufB, 3); BARRIER();
    }

    // L34: D (64 rows) -> E. Output node n=q*4+r; L56 parent m=q, child s=r
    // -> E row = 2q+(r&1)+32*(r>>1) in {0..7, 32..39} of bufA (A is dead).
    {
        f32x4 a2[2];
        quad_acc<16>(bufD, w2a, w2b, b2v, q, lm, a2);
#pragma unroll
        for (int nl = 0; nl < 2; ++nl) {
            const int col = (2 * wv + nl) * 16 + lm;
            const bf16x4 hv = __builtin_convertvector(a2[nl], bf16x4);
#pragma unroll
            for (int r = 0; r < 4; ++r) {
                const int row = 2 * q + (r & 1) + 32 * (r >> 1);
                bufA[row * STRIDE + col] = hv[r];
            }
        }
    }
    BARRIER();
    // L56: E (16 nodes) -> 4 roots straight to y (rows 0..3 live at q==0).
    {
        f32x4 a2[2];
        quad_acc<4>(bufA, w2a, w2b, b2v, q, lm, a2);
        __bf16* yrow = yout + (size_t)(batch * 32 + pair * 4) * 128;
#pragma unroll
        for (int nl = 0; nl < 2; ++nl) {
            const int col = (2 * wv + nl) * 16 + lm;
            if (q == 0) {
#pragma unroll
                for (int r = 0; r < 4; ++r)
                    yrow[r * 128 + col] = (__bf16)a2[nl][r];
            }
        }
    }
}

// ---- tree32: byte-identical to r9 (proven) ----
template <int NOUT>
__device__ __forceinline__ void quad_acc_res(
    const __bf16* src, const bf16x8* w2r,
    const float* b2v, int q, int lm, f32x4 (&acc)[2])
{
    const int me = (NOUT >= 16) ? lm : (lm < NOUT ? lm : 0);
    acc[0] = f32x4{ b2v[0], b2v[0], b2v[0], b2v[0] };
    acc[1] = f32x4{ b2v[1], b2v[1], b2v[1], b2v[1] };
#pragma unroll
    for (int kk = 0; kk < 16; ++kk) {
        const bf16x8 af = *(const bf16x8*)
            &src[((kk >> 2) * NOUT + me) * STRIDE + (kk & 3) * 32 + q * 8];
        acc[0] = __builtin_amdgcn_mfma_f32_16x16x32_bf16(
            af, w2r[kk], acc[0], 0, 0, 0);
        acc[1] = __builtin_amdgcn_mfma_f32_16x16x32_bf16(
            af, w2r[16 + kk], acc[1], 0, 0, 0);
    }
}

__global__ __launch_bounds__(256) void tree32_kernel(
    const __bf16* __restrict__ yin, const __bf16* __restrict__ wpack1,
    const __bf16* __restrict__ wpack2, const float* __restrict__ b2,
    const float* __restrict__ bias, float* __restrict__ out)
{
    __shared__ __align__(16) __bf16 buf0[32 * STRIDE];  // 8704 B
    __shared__ __align__(16) __bf16 buf1[8 * STRIDE];   // 2176 B
    const int tid = threadIdx.x;
    const int batch = blockIdx.x;
    const int wv = tid >> 6, ln = tid & 63, q = ln >> 4, lm = ln & 15;

    bf16x8 w2r[32];
    const bf16x8* wp2 = (const bf16x8*)wpack2;
#pragma unroll
    for (int f = 0; f < 32; ++f) w2r[f] = wp2[f * 256 + tid];
    bf16x8 w1r[16];
    const bf16x8* wp1 = (const bf16x8*)wpack1;
#pragma unroll
    for (int f = 0; f < 16; ++f) w1r[f] = wp1[f * 256 + tid];
    float b2v[2], b1v[2];
    b2v[0] = b2[(2 * wv + 0) * 16 + lm];
    b2v[1] = b2[(2 * wv + 1) * 16 + lm];
    b1v[0] = bias[(2 * wv + 0) * 16 + lm];
    b1v[1] = bias[(2 * wv + 1) * 16 + lm];

#pragma unroll
    for (int i = 0; i < 2; ++i) {
        const int flat = tid + 256 * i;
        const int o = flat >> 4;
        const int c8 = flat & 15;
        const bf16x8 v =
            *(const bf16x8*)(yin + (size_t)(batch * 32 + o) * 128 + c8 * 8);
        *(bf16x8*)&buf0[((o & 3) * 8 + (o >> 2)) * STRIDE + c8 * 8] = v;
    }
    __syncthreads();

    // Q1: 32 -> 8 (perm rows r*2+q for the NOUT=2 read).
    {
        f32x4 a2[2];
        quad_acc_res<8>(buf0, w2r, b2v, q, lm, a2);
#pragma unroll
        for (int nl = 0; nl < 2; ++nl) {
            const int col = (2 * wv + nl) * 16 + lm;
            const bf16x4 hv = __builtin_convertvector(a2[nl], bf16x4);
            if (q < 2) {
#pragma unroll
                for (int r = 0; r < 4; ++r)
                    buf1[(r * 2 + q) * STRIDE + col] = hv[r];
            }
        }
    }
    __syncthreads();
    // Q2: 8 -> 2 (plain rows 0,1 for the W1 final).
    {
        f32x4 a2[2];
        quad_acc_res<2>(buf1, w2r, b2v, q, lm, a2);
#pragma unroll
        for (int nl = 0; nl < 2; ++nl) {
            const int col = (2 * wv + nl) * 16 + lm;
            const bf16x4 hv = __builtin_convertvector(a2[nl], bf16x4);
            if (q == 0) {
#pragma unroll
                for (int r = 0; r < 2; ++r)
                    buf0[r * STRIDE + col] = hv[r];
            }
        }
    }
    __syncthreads();
    // Final: rows 0,1 (K=256, W1, bias b) -> fp32 root row.
    {
        f32x4 acc[2];
        acc[0] = f32x4{ b1v[0], b1v[0], b1v[0], b1v[0] };
        acc[1] = f32x4{ b1v[1], b1v[1], b1v[1], b1v[1] };
#pragma unroll
        for (int kh = 0; kh < 2; ++kh) {
            bf16x8 af[4];
#pragma unroll
            for (int j = 0; j < 4; ++j)
                af[j] = *(const bf16x8*)&buf0[kh * STRIDE + j * 32 + q * 8];
#pragma unroll
            for (int nl = 0; nl < 2; ++nl)
#pragma unroll
                for (int j = 0; j < 4; ++j)
                    acc[nl] = __builtin_amdgcn_mfma_f32_16x16x32_bf16(
                        af[j], w1r[nl * 8 + kh * 4 + j], acc[nl], 0, 0, 0);
        }
#pragma unroll
        for (int nl = 0; nl < 2; ++nl) {
            const int col = (2 * wv + nl) * 16 + lm;
            if (q == 0) out[(size_t)batch * 128 + col] = acc[nl][0];
        }
    }
}

extern "C" void kernel_launch(void* const* d_in, const int* in_sizes, int n_in,
                              void* d_out, int out_size, void* d_ws, size_t ws_size,
                              hipStream_t stream) {
    const int*   wid = (const int*)d_in[0];      // (256, 2048) int32
    const float* emb = (const float*)d_in[1];    // (100000, 128) fp32
    const float* W   = (const float*)d_in[2];    // (128, 256) fp32
    const float* b   = (const float*)d_in[3];    // (128,) fp32
    float* out = (float*)d_out;                  // (256, 128) fp32

    __bf16* wpack1 = (__bf16*)d_ws;              // 32768 bf16 = 64 KB
    __bf16* wpack2 = wpack1 + 32768;             // 65536 bf16 = 128 KB
    float*  b2     = (float*)(wpack2 + 65536);   // 128 f32 = 512 B
    __bf16* y      = (__bf16*)(b2 + 128);        // (256,32,128) bf16 = 2 MB
    __bf16* etab   = y + 256 * 32 * 128;         // (100000,128) bf16 = 25.6 MB

    const size_t need_full = (size_t)(32768 + 65536) * 2 + 512
                           + (size_t)256 * 32 * 128 * 2
                           + (size_t)100000 * 128 * 2;   // ~27.9 MB
    const bool bf = (ws_size >= need_full);
    const int n8 = bf ? (100000 * 128 / 8) : 0;

    prep_kernel<<<2048, 256, 0, stream>>>(W, b, emb, wpack1, wpack2, b2,
                                          etab, n8);
    if (bf)
        tree128_kernel<true><<<2048, 256, 0, stream>>>(
            wid, emb, etab, wpack2, b2, y);
    else
        tree128_kernel<false><<<2048, 256, 0, stream>>>(
            wid, emb, etab, wpack2, b2, y);
    tree32_kernel<<<256, 256, 0, stream>>>(y, wpack1, wpack2, b2, b, out);
}